// Round 5
// baseline (3084.720 us; speedup 1.0000x reference)
//
#include <hip/hip_runtime.h>
#include <hip/hip_bf16.h>
#include <hip/hip_fp16.h>

// ---------------------------------------------------------------------------
// 3-layer GRU (Keras v2, reset_after=True), B=64 T=2048 F=H=128, OUT=5.
// Round 11: CO-RESIDENT PRODUCER WGs (1:1), coalesced f32 xw ring.
//   Evidence r4-r10: step = issue(~890cy incl proj) + stall(~1000-1300cy);
//   bare step (r4/r5, xw precomputed) = ~340cy issue -> ~1100cy step. Proj
//   must leave the rec instruction stream entirely:
//    r7  same-WG waves: shared barrier lockstep -> fail
//    r8  same-thread ILP: works but halves CUs -> fail
//    r6/r10 proj in-stream (inline or chunk-block): +550cy issue/step -> flat
//    r9  global ring: right idea; 4B scatter writes (1.28GB) + 1:3 under-
//        provisioned proj -> fail
//   => 384 WGs = 192 rec + 192 proj (1:1), proj co-resident on the same
//   XCD (blk order keeps both = b mod 8). Rec = bare recurrence + ring
//   staging only. Proj writes xw chunks COALESCED (LDS transpose + float4)
//   into a RING=4 f32 ring; ~10% duty. No shared barriers; no CU loss;
//   proj issue fills rec stall slots (m114 co-issue).
//   Flags (steps units): hflag[l][b] rec progress (also ring backpressure),
//   pflag[l][b] proj progress. Deadlock-audited: proj blocked at chunk i
//   => rec boundary < i-3 => rec's wait (pflag>=(c+2)CHK<=(i-1)CHK) is
//   satisfied (proj produced through i-1) -> rec advances. RING=4 > 2-chunk
//   rec lookahead + 1.
// ws: 3 h-planes f16 (100.7MB) + xw ring f32 (18.9MB) + 384 flags.
// ---------------------------------------------------------------------------

#define HID   128
#define H3    384
#define OUTD  5
#define CHK   16            // steps per chunk (publish/poll granularity)
#define RING  4             // xw ring depth in chunks
#define NREC  192           // rec WGs (3 layers x 64 batches); proj = same

typedef _Float16 f16x2 __attribute__((ext_vector_type(2)));
typedef _Float16 f16x4 __attribute__((ext_vector_type(4)));
typedef _Float16 f16x8 __attribute__((ext_vector_type(8)));

__device__ __forceinline__ float fdot2(f16x2 a, f16x2 b, float c) {
#if __has_builtin(__builtin_amdgcn_fdot2)
    return __builtin_amdgcn_fdot2(a, b, c, false);   // v_dot2_f32_f16
#else
    return fmaf((float)a.x, (float)b.x, fmaf((float)a.y, (float)b.y, c));
#endif
}

__device__ __forceinline__ float fexp2(float x) {
#if __has_builtin(__builtin_amdgcn_exp2f)
    return __builtin_amdgcn_exp2f(x);
#else
    return exp2f(x);
#endif
}

__device__ __forceinline__ float frcp(float x) {
#if __has_builtin(__builtin_amdgcn_rcpf)
    return __builtin_amdgcn_rcpf(x);
#else
    return 1.f / x;
#endif
}

// sigmoid(x) = 1/(1+exp(-x)); saturates correctly at +-inf.
__device__ __forceinline__ float fsigmoid(float x) {
    return frcp(1.f + fexp2(x * -1.4426950408889634f));
}

// tanh(x) = 1 - 2/(1+exp(2x)); saturates correctly at +-inf.
__device__ __forceinline__ float ftanh_(float x) {
    return fmaf(-2.f, frcp(1.f + fexp2(x * 2.8853900817779268f)), 1.f);
}

// barrier that does NOT drain vmcnt (unlike __syncthreads): LDS handoff only.
__device__ __forceinline__ void soft_barrier() {
    asm volatile("s_waitcnt lgkmcnt(0)\n\ts_barrier" ::: "memory");
}

// butterfly sum over the kh quad (lanes xor 1, xor 2) on the VALU pipe
__device__ __forceinline__ float quad_sum(float x) {
#if __has_builtin(__builtin_amdgcn_mov_dpp)
    int i1 = __builtin_amdgcn_mov_dpp(__float_as_int(x), 0xB1, 0xF, 0xF, true); // [1,0,3,2]
    x += __int_as_float(i1);
    int i2 = __builtin_amdgcn_mov_dpp(__float_as_int(x), 0x4E, 0xF, 0xF, true); // [2,3,0,1]
    x += __int_as_float(i2);
#else
    x += __shfl_xor(x, 1);
    x += __shfl_xor(x, 2);
#endif
    return x;
}

// ---------------------------------------------------------------------------
__global__ void zero_flags(int* f) {
    if (threadIdx.x < 2 * NREC) f[threadIdx.x] = 0;
}

// ---------------------------------------------------------------------------
// gru_pipe: 384 WGs, 512 thr.
//  blk <  192: REC role (layer = blk>>6, b = blk&63). Bare recurrence:
//    per step 3 x b32 xw broadcast reads + 4 x b128 h reads + 48 fdot2 +
//    DPP reduce + gates + h LDS/global store + soft_barrier (~85 instrs).
//    Ring chunk staged: float4 loads at boundary, LDS write at ts==7.
//  blk >= 192: PROJ role for (layer,b) = blk-192. Per chunk: stage input
//    (x or h[l-1]) -> LDS f16; 768 fdot2/thread (2-row ILP); DPP reduce;
//    xwp LDS f32; coalesced float4 copy into ring slot; release pflag.
// ---------------------------------------------------------------------------
__global__ __launch_bounds__(512, 2) void gru_pipe(
    const float* __restrict__ x,                         // [64,T,128] fp32
    const float* __restrict__ k0, const float* __restrict__ k1, const float* __restrict__ k2,
    const float* __restrict__ rk0, const float* __restrict__ rk1, const float* __restrict__ rk2,
    const float* __restrict__ b0, const float* __restrict__ b1, const float* __restrict__ b2,
    _Float16* __restrict__ hpl0, _Float16* __restrict__ hpl1, _Float16* __restrict__ hpl2,
    float* __restrict__ xwr,                             // ring [3][64][RING][CHK][384] f32
    int* flags, int T)
{
    const int blk = blockIdx.x;
    const int t   = threadIdx.x;      // 0..511
    const int NC  = T / CHK;          // 128 chunks

    // union'd LDS: rec uses 49664B, proj uses 28672B
    __shared__ __align__(16) char lds_raw[49664];

    const int j   = t >> 2;           // unit 0..127
    const int kh  = t & 3;            // k-quarter
    const int k0i = kh * 32;

    if (blk < NREC) {
        // =================== RECURRENT ROLE ====================
        const int layer = blk >> 6;
        const int b     = blk & 63;

        float    (*xwc)[CHK][H3] = (float(*)[CHK][H3])lds_raw;        // [2][16][384] f32
        _Float16 (*hb)[HID]      = (_Float16(*)[HID])(lds_raw + 49152); // [2][128] f16

        const float* Rw = (layer == 0) ? rk0 : (layer == 1) ? rk1 : rk2;
        const float* Bs = (layer == 0) ? b0  : (layer == 1) ? b1  : b2;
        _Float16* hout = (layer == 0) ? hpl0 : (layer == 1) ? hpl1 : hpl2;

        f16x2 wzR[16], wrR[16], whR[16];              // 48 VGPRs
#pragma unroll
        for (int p = 0; p < 16; ++p) {
            const int k = k0i + 2 * p;
            const float* r0p = Rw + (size_t)k * H3;
            const float* r1p = r0p + H3;
            f16x2 a;
            a.x = (_Float16)r0p[j];       a.y = (_Float16)r1p[j];       wzR[p] = a;
            a.x = (_Float16)r0p[j + 128]; a.y = (_Float16)r1p[j + 128]; wrR[p] = a;
            a.x = (_Float16)r0p[j + 256]; a.y = (_Float16)r1p[j + 256]; whR[p] = a;
        }
        const float bhR = Bs[H3 + 256 + j];           // b_rec(h) (inside r*)

        int* hflag = flags + layer * 64 + b;
        int* pflag = flags + NREC + layer * 64 + b;

        _Float16* hob = hout + (size_t)b * T * HID;
        const float4* ring4 = (const float4*)(xwr + (size_t)(layer * 64 + b) * RING * CHK * H3);

        // stage one ring chunk: 16 rows x 384 f32 = 1536 float4; 3/thread.
        float4 sreg[3];
        auto stage_load = [&](int cc) {
            const float4* base = ring4 + (size_t)(cc & (RING - 1)) * (CHK * H3 / 4);
#pragma unroll
            for (int i = 0; i < 3; ++i) sreg[i] = base[t + 512 * i];
        };
        auto stage_write = [&](int cc) {
            float4* dst = (float4*)(&xwc[cc & 1][0][0]);
#pragma unroll
            for (int i = 0; i < 3; ++i) dst[t + 512 * i] = sreg[i];
        };

        if (t < HID) { hb[0][t] = (_Float16)0.f; hb[1][t] = (_Float16)0.f; }

        // ---- prologue: wait xw chunk 0, stage it ----
        if (t == 0) {
            while (__hip_atomic_load(pflag, __ATOMIC_ACQUIRE, __HIP_MEMORY_SCOPE_AGENT) < CHK)
                __builtin_amdgcn_s_sleep(4);
        }
        __syncthreads();
        stage_load(0);
        stage_write(0);      // vmcnt wait here (prologue only)

        float h_old = 0.f;
        for (int c = 0; c < NC; ++c) {
            __syncthreads();   // A: drains vm+lgkm (prev chunk h stores + staging)
            if (t == 0) {
                if (c > 0)
                    __hip_atomic_store(hflag, c * CHK, __ATOMIC_RELEASE, __HIP_MEMORY_SCOPE_AGENT);
                if (c + 1 < NC) {
                    while (__hip_atomic_load(pflag, __ATOMIC_ACQUIRE, __HIP_MEMORY_SCOPE_AGENT) < (c + 2) * CHK)
                        __builtin_amdgcn_s_sleep(4);
                }
            }
            __syncthreads();   // B
            if (c + 1 < NC) stage_load(c + 1);   // ring slot -> regs; ~8 steps in flight

            const float* xrow = &xwc[c & 1][0][0];
#pragma unroll 2
            for (int ts = 0; ts < CHK; ++ts) {
                const int tstep = c * CHK + ts;
                const int rbuf  = ts & 1;

                // xw from staged chunk (quad-broadcast ds_read_b32)
                const float xz = xrow[ts * H3 + j];
                const float xr = xrow[ts * H3 + 128 + j];
                const float xh = xrow[ts * H3 + 256 + j];

                // recurrent dot from own h state
                const f16x8* hp = (const f16x8*)(&hb[rbuf][k0i]);
                float sz = 0.f, sr = 0.f, sh = 0.f;
#pragma unroll
                for (int i = 0; i < 4; ++i) {
                    union { f16x8 v; f16x2 p[4]; } u;
                    u.v = hp[i];
#pragma unroll
                    for (int q = 0; q < 4; ++q) {
                        sz = fdot2(u.p[q], wzR[4 * i + q], sz);
                        sr = fdot2(u.p[q], wrR[4 * i + q], sr);
                        sh = fdot2(u.p[q], whR[4 * i + q], sh);
                    }
                }
                sz = quad_sum(sz); sr = quad_sum(sr); sh = quad_sum(sh);

                const float z  = fsigmoid(xz + sz);
                const float r  = fsigmoid(xr + sr);
                const float hh = ftanh_(xh + (sh + bhR) * r);
                const float hn = fmaf(z, h_old - hh, hh);
                h_old = hn;

                if (kh == 0) {
                    hb[rbuf ^ 1][j] = (_Float16)hn;
                    hob[(size_t)tstep * HID + j] = (_Float16)hn;
                }

                if (ts == 7 && c + 1 < NC) stage_write(c + 1);  // vmcnt hidden

                soft_barrier();   // lgkm-only: global loads/stores stay in flight
            }
        }

        __syncthreads();
        if (t == 0)
            __hip_atomic_store(hflag, T, __ATOMIC_RELEASE, __HIP_MEMORY_SCOPE_AGENT);

    } else {
        // =================== PROJECTION ROLE ====================
        const int pb    = blk - NREC;
        const int layer = pb >> 6;
        const int b     = pb & 63;

        _Float16 (*insp)[HID] = (_Float16(*)[HID])lds_raw;            // [16][128] f16
        float    (*xwp)[H3]   = (float(*)[H3])(lds_raw + 4096);       // [16][384] f32

        const float* Kw = (layer == 0) ? k0 : (layer == 1) ? k1 : k2;
        const float* Bs = (layer == 0) ? b0 : (layer == 1) ? b1 : b2;

        f16x2 wzK[16], wrK[16], whK[16];              // 48 VGPRs
#pragma unroll
        for (int p = 0; p < 16; ++p) {
            const int k = k0i + 2 * p;
            const float* c0 = Kw + (size_t)k * H3;
            const float* c1 = c0 + H3;
            f16x2 a;
            a.x = (_Float16)c0[j];       a.y = (_Float16)c1[j];       wzK[p] = a;
            a.x = (_Float16)c0[j + 128]; a.y = (_Float16)c1[j + 128]; wrK[p] = a;
            a.x = (_Float16)c0[j + 256]; a.y = (_Float16)c1[j + 256]; whK[p] = a;
        }
        const float bz = Bs[j]       + Bs[H3 + j];         // b_in(z)+b_rec(z)
        const float br = Bs[128 + j] + Bs[H3 + 128 + j];   // b_in(r)+b_rec(r)
        const float bh = Bs[256 + j];                      // b_in(h)

        int* myp   = flags + NREC + layer * 64 + b;        // own pflag
        int* hin_f = flags + (layer - 1) * 64 + b;         // hflag(l-1), l>0
        int* own_f = flags + layer * 64 + b;               // hflag(l): backpressure

        const float*    xbp = x + (size_t)b * T * HID;
        const _Float16* hib = ((layer == 1) ? hpl0 : hpl1) + (size_t)b * T * HID;
        float* ringb = xwr + (size_t)(layer * 64 + b) * RING * CHK * H3;

        const int srow  = t >> 5;          // staging row 0..15
        const int scol4 = (t & 31) * 4;    // 4 f16 per thread

        for (int cc = 0; cc < NC; ++cc) {
            // waits: input readiness (l>0) + ring backpressure
            if (t == 0) {
                if (layer > 0) {
                    while (__hip_atomic_load(hin_f, __ATOMIC_ACQUIRE, __HIP_MEMORY_SCOPE_AGENT) < (cc + 1) * CHK)
                        __builtin_amdgcn_s_sleep(4);
                }
                if (cc >= RING) {
                    while (__hip_atomic_load(own_f, __ATOMIC_ACQUIRE, __HIP_MEMORY_SCOPE_AGENT) < (cc - (RING - 1)) * CHK)
                        __builtin_amdgcn_s_sleep(4);
                }
            }
            __syncthreads();   // gates the stage loads on the waits

            // stage input chunk cc -> insp (f16 [16][128])
            if (layer == 0) {
                const float4 v = *(const float4*)(xbp + (size_t)(cc * CHK + srow) * HID + scol4);
                f16x4 o;
                o[0] = (_Float16)v.x; o[1] = (_Float16)v.y;
                o[2] = (_Float16)v.z; o[3] = (_Float16)v.w;
                *(f16x4*)(&insp[srow][scol4]) = o;
            } else {
                *(f16x4*)(&insp[srow][scol4]) =
                    *(const f16x4*)(hib + (size_t)(cc * CHK + srow) * HID + scol4);
            }
            __syncthreads();

            // compute: 16 rows x 3 gates, rows 2-at-a-time (ILP)
#pragma unroll 2
            for (int rp = 0; rp < 8; ++rp) {
                const int r0 = 2 * rp, r1 = r0 + 1;
                const f16x8* p0 = (const f16x8*)(&insp[r0][k0i]);
                const f16x8* p1 = (const f16x8*)(&insp[r1][k0i]);
                float az0 = 0.f, ar0 = 0.f, ah0 = 0.f;
                float az1 = 0.f, ar1 = 0.f, ah1 = 0.f;
#pragma unroll
                for (int i = 0; i < 4; ++i) {
                    union { f16x8 v; f16x2 p[4]; } u0, u1;
                    u0.v = p0[i]; u1.v = p1[i];
#pragma unroll
                    for (int q = 0; q < 4; ++q) {
                        az0 = fdot2(u0.p[q], wzK[4 * i + q], az0);
                        az1 = fdot2(u1.p[q], wzK[4 * i + q], az1);
                        ar0 = fdot2(u0.p[q], wrK[4 * i + q], ar0);
                        ar1 = fdot2(u1.p[q], wrK[4 * i + q], ar1);
                        ah0 = fdot2(u0.p[q], whK[4 * i + q], ah0);
                        ah1 = fdot2(u1.p[q], whK[4 * i + q], ah1);
                    }
                }
                az0 = quad_sum(az0); ar0 = quad_sum(ar0); ah0 = quad_sum(ah0);
                az1 = quad_sum(az1); ar1 = quad_sum(ar1); ah1 = quad_sum(ah1);
                if (kh == 0) {
                    xwp[r0][j] = az0 + bz; xwp[r0][128 + j] = ar0 + br; xwp[r0][256 + j] = ah0 + bh;
                    xwp[r1][j] = az1 + bz; xwp[r1][128 + j] = ar1 + br; xwp[r1][256 + j] = ah1 + bh;
                }
            }
            __syncthreads();

            // coalesced copy xwp -> ring slot (1536 float4, 3/thread)
            {
                float4* d4 = (float4*)(ringb + (size_t)(cc & (RING - 1)) * CHK * H3);
                const float4* s4 = (const float4*)(&xwp[0][0]);
#pragma unroll
                for (int i = 0; i < 3; ++i) d4[t + 512 * i] = s4[t + 512 * i];
            }
            __syncthreads();   // drains vm (ring stores complete) before release
            if (t == 0)
                __hip_atomic_store(myp, (cc + 1) * CHK, __ATOMIC_RELEASE, __HIP_MEMORY_SCOPE_AGENT);
        }
    }
}

// ---------------------------------------------------------------------------
// out_proj: out[r,:] = h_f16[r,:] @ wo + bo (fp32 out). Thread = row.
// ---------------------------------------------------------------------------
__global__ __launch_bounds__(256) void out_proj(
    const _Float16* __restrict__ Hf,  // [R,128] f16
    const float* __restrict__ wo,     // [128,5]
    const float* __restrict__ bo,     // [5]
    float*       __restrict__ out,    // [R,5]
    int R)
{
    const int r = blockIdx.x * 256 + threadIdx.x;
    if (r >= R) return;
    const f16x8* xp = (const f16x8*)(Hf + (size_t)r * HID);

    float a0 = bo[0], a1 = bo[1], a2 = bo[2], a3 = bo[3], a4 = bo[4];
#pragma unroll 4
    for (int c = 0; c < 16; ++c) {
        const f16x8 v = xp[c];
#pragma unroll
        for (int e = 0; e < 8; ++e) {
            const float xv = (float)v[e];
            const float* w = wo + (size_t)(8 * c + e) * OUTD;
            a0 = fmaf(xv, w[0], a0);
            a1 = fmaf(xv, w[1], a1);
            a2 = fmaf(xv, w[2], a2);
            a3 = fmaf(xv, w[3], a3);
            a4 = fmaf(xv, w[4], a4);
        }
    }
    float* op = out + (size_t)r * OUTD;
    op[0] = a0; op[1] = a1; op[2] = a2; op[3] = a3; op[4] = a4;
}

// ---------------------------------------------------------------------------
extern "C" void kernel_launch(void* const* d_in, const int* in_sizes, int n_in,
                              void* d_out, int out_size, void* d_ws, size_t ws_size,
                              hipStream_t stream) {
    const float* x   = (const float*)d_in[0];
    const float* k0  = (const float*)d_in[1];
    const float* rk0 = (const float*)d_in[2];
    const float* b0  = (const float*)d_in[3];
    const float* k1  = (const float*)d_in[4];
    const float* rk1 = (const float*)d_in[5];
    const float* b1  = (const float*)d_in[6];
    const float* k2  = (const float*)d_in[7];
    const float* rk2 = (const float*)d_in[8];
    const float* b2  = (const float*)d_in[9];
    const float* wo  = (const float*)d_in[10];
    const float* bo  = (const float*)d_in[11];
    float* out = (float*)d_out;

    const int BT = in_sizes[0] / HID;   // 64*2048 = 131072 rows
    const int B  = 64;
    const int T  = BT / B;              // 2048

    // ws layout: 3 f16 h-planes + f32 xw ring + flags
    const size_t plane = (size_t)BT * HID * sizeof(_Float16);               // 33.55MB
    const size_t ringb = (size_t)3 * 64 * RING * CHK * H3 * sizeof(float);  // 18.87MB
    _Float16* hpl0 = (_Float16*)d_ws;
    _Float16* hpl1 = (_Float16*)((char*)d_ws + plane);
    _Float16* hpl2 = (_Float16*)((char*)d_ws + 2 * plane);
    float*    xwr  = (float*)((char*)d_ws + 3 * plane);
    int*      flags = (int*)((char*)d_ws + 3 * plane + ringb);

    zero_flags<<<1, 512, 0, stream>>>(flags);
    gru_pipe  <<<2 * NREC, 512, 0, stream>>>(x, k0, k1, k2, rk0, rk1, rk2,
                                             b0, b1, b2, hpl0, hpl1, hpl2, xwr, flags, T);
    out_proj  <<<(BT + 255) / 256, 256, 0, stream>>>(hpl2, wo, bo, out, BT);
}

// Round 6
// 2631.753 us; speedup vs baseline: 1.1721x; 1.1721x over previous
//
#include <hip/hip_runtime.h>
#include <hip/hip_bf16.h>
#include <hip/hip_fp16.h>

// ---------------------------------------------------------------------------
// 3-layer GRU (Keras v2, reset_after=True), B=64 T=2048 F=H=128, OUT=5.
// Round 12: MFMA-BATCHED RECURRENCE. MfmaUtil was 0.0 all session while we
// fought VALU issue (~890cy/step of fdot2) and LDS broadcast. Both the
// recurrence H(16x128)@R(128x384) and the input projection are MFMA GEMMs.
//   12 WGs = 3 layers x 4 groups of 16 batches, 512 thr (8 waves).
//   Wave w owns unit-blocks {w, w+8, w+16} (cols 16w+.. of z, r, h gates) so
//   z/r/h of a (batch,unit) land in the SAME lane; gates = in-lane VALU;
//   biases fold into MFMA C-init. h_old lives in C-layout regs.
//   Per step/wave: 12 MFMA rec + 12 MFMA xw(t+1) + 4 ds_read_b128 (H frags,
//   XOR-swizzled dbuf) + 4 ds_write_b16 + 4 global_load (X frags, 3 steps
//   ahead, global->reg) + 4 global_store_short (h-plane) + ~85 VALU gates.
//   One lgkm-only barrier per step. Layer handoff: r6's proven chunk-flag
//   protocol (CHK=16, agent-scope release/acquire), 4 flags/layer.
//   MFMA layouts (16x16x32 f16): A row=lane&15, k=(lane>>4)*8+e;
//   B col=lane&15, k=(lane>>4)*8+e; C col=lane&15 (unit), row=(lane>>4)*4+q
//   (batch) [guide-verified C; standard A/B].
// ws: 3 h-planes f16 (33.55MB each) + x16 plane (33.55MB) + 12 flags.
// ---------------------------------------------------------------------------

#define HID   128
#define H3    384
#define OUTD  5
#define CHK   16

typedef _Float16 f16x8 __attribute__((ext_vector_type(8)));
typedef float    f32x4 __attribute__((ext_vector_type(4)));

#define SPLAT4(v) ((f32x4){(v), (v), (v), (v)})

__device__ __forceinline__ float fexp2(float x) {
#if __has_builtin(__builtin_amdgcn_exp2f)
    return __builtin_amdgcn_exp2f(x);
#else
    return exp2f(x);
#endif
}

__device__ __forceinline__ float frcp(float x) {
#if __has_builtin(__builtin_amdgcn_rcpf)
    return __builtin_amdgcn_rcpf(x);
#else
    return 1.f / x;
#endif
}

// sigmoid(x) = 1/(1+exp(-x)); saturates correctly at +-inf.
__device__ __forceinline__ float fsigmoid(float x) {
    return frcp(1.f + fexp2(x * -1.4426950408889634f));
}

// tanh(x) = 1 - 2/(1+exp(2x)); saturates correctly at +-inf.
__device__ __forceinline__ float ftanh_(float x) {
    return fmaf(-2.f, frcp(1.f + fexp2(x * 2.8853900817779268f)), 1.f);
}

// barrier that does NOT drain vmcnt (unlike __syncthreads): LDS handoff only.
__device__ __forceinline__ void soft_barrier() {
    asm volatile("s_waitcnt lgkmcnt(0)\n\ts_barrier" ::: "memory");
}

// ---------------------------------------------------------------------------
__global__ void zero_flags(int* f) {
    if (threadIdx.x < 12) f[threadIdx.x] = 0;
}

// x f32 -> f16 plane (one-shot, ~25us)
__global__ __launch_bounds__(256) void xcvt(
    const float* __restrict__ x, _Float16* __restrict__ y, int n8) {
    const int i = blockIdx.x * 256 + threadIdx.x;
    if (i >= n8) return;
    const float4 a = ((const float4*)x)[2 * i];
    const float4 b = ((const float4*)x)[2 * i + 1];
    f16x8 o;
    o[0] = (_Float16)a.x; o[1] = (_Float16)a.y; o[2] = (_Float16)a.z; o[3] = (_Float16)a.w;
    o[4] = (_Float16)b.x; o[5] = (_Float16)b.y; o[6] = (_Float16)b.z; o[7] = (_Float16)b.w;
    ((f16x8*)y)[i] = o;
}

// ---------------------------------------------------------------------------
// gru12: 12 WGs, 512 thr. layer = blk>>2, group g = blk&3 (batches 16g..).
// ---------------------------------------------------------------------------
__global__ __launch_bounds__(512, 1) void gru12(
    const _Float16* __restrict__ x16,                    // [64,T,128] f16
    const float* __restrict__ k0, const float* __restrict__ k1, const float* __restrict__ k2,
    const float* __restrict__ rk0, const float* __restrict__ rk1, const float* __restrict__ rk2,
    const float* __restrict__ b0, const float* __restrict__ b1, const float* __restrict__ b2,
    _Float16* __restrict__ hpl0, _Float16* __restrict__ hpl1, _Float16* __restrict__ hpl2,
    int* flags, int T)
{
    const int blk   = blockIdx.x;
    const int layer = blk >> 2;        // 0..2
    const int g     = blk & 3;         // batch-group
    const int bg    = g * 16;
    const int t     = threadIdx.x;     // 0..511
    const int w     = t >> 6;          // wave 0..7 -> unit-block
    const int l     = t & 63;
    const int li    = l & 15;          // A-row (batch) on reads / col (unit) on C
    const int lg    = l >> 4;          // k-group on reads / batch-group on C
    const int NC    = T / CHK;

    const float* Kw = (layer == 0) ? k0  : (layer == 1) ? k1  : k2;
    const float* Rw = (layer == 0) ? rk0 : (layer == 1) ? rk1 : rk2;
    const float* Bs = (layer == 0) ? b0  : (layer == 1) ? b1  : b2;
    const _Float16* xin = (layer == 0) ? x16 : (layer == 1) ? hpl0 : hpl1;
    _Float16* hout = (layer == 0) ? hpl0 : (layer == 1) ? hpl1 : hpl2;

    // H double buffer, [slot][b*128+u] f16, XOR-swizzled (byte^=(b&7)<<4)
    __shared__ __align__(16) _Float16 Hs[2][2048];
    _Float16* hsp = &Hs[0][0];

    // ---- B-fragment preload: R and K, 3 gates x 4 k-tiles, f16x8 each ----
    f16x8 RB[3][4], KB[3][4];
#pragma unroll
    for (int gi = 0; gi < 3; ++gi) {
        const int col = 16 * w + 128 * gi + li;
        const float* Rc = Rw + col;
        const float* Kc = Kw + col;
#pragma unroll
        for (int kt = 0; kt < 4; ++kt) {
            f16x8 rv, kv;
#pragma unroll
            for (int e = 0; e < 8; ++e) {
                const int k = kt * 32 + lg * 8 + e;
                rv[e] = (_Float16)Rc[(size_t)k * H3];
                kv[e] = (_Float16)Kc[(size_t)k * H3];
            }
            RB[gi][kt] = rv;
            KB[gi][kt] = kv;
        }
    }
    const int uz = 16 * w + li;                       // this lane's unit
    const float bin0 = Bs[uz];                        // b_in(z)
    const float bin1 = Bs[128 + uz];                  // b_in(r)
    const float bin2 = Bs[256 + uz];                  // b_in(h)
    const float brc0 = Bs[H3 + uz];                   // b_rec(z)
    const float brc1 = Bs[H3 + 128 + uz];             // b_rec(r)
    const float brc2 = Bs[H3 + 256 + uz];             // b_rec(h)

    // ---- LDS addresses (bytes, step-invariant; slot = +4096 via index) ----
    int hr[4], hw[4];
#pragma unroll
    for (int kt = 0; kt < 4; ++kt) {
        const int a = li * 256 + kt * 64 + lg * 16;   // read: b=li, k-block
        hr[kt] = a ^ ((li & 7) << 4);
    }
#pragma unroll
    for (int q = 0; q < 4; ++q) {
        const int b = lg * 4 + q;                     // write: batch, unit uz
        const int a = b * 256 + uz * 2;
        hw[q] = a ^ ((b & 7) << 4);
    }

    // input A-frag base: batch bg+li, k-offset lg*8
    const _Float16* inb = xin + ((size_t)(bg + li) * T) * HID + lg * 8;

    // output pointers: batch bg+lg*4+q, unit uz
    _Float16* hpq[4];
#pragma unroll
    for (int q = 0; q < 4; ++q)
        hpq[q] = hout + ((size_t)(bg + lg * 4 + q) * T) * HID + uz;

    int* myflag = flags + layer * 4 + g;
    int* sflag  = flags + (layer - 1) * 4 + g;

    // zero H (both slots): 8192B = 512 x float4
    ((float4*)hsp)[t] = float4{0.f, 0.f, 0.f, 0.f};

    // ---- prologue ----
    if (layer > 0 && t == 0) {
        while (__hip_atomic_load(sflag, __ATOMIC_ACQUIRE, __HIP_MEMORY_SCOPE_AGENT) < CHK)
            __builtin_amdgcn_s_sleep(4);
    }
    __syncthreads();

    f16x8 bb[2][4];
    f32x4 XAz, XAr, XAh, XBz, XBr, XBh;
    f32x4 hold = SPLAT4(0.f);

    // X[0] -> bb[0], xw[0] -> XA
#pragma unroll
    for (int kt = 0; kt < 4; ++kt)
        bb[0][kt] = *(const f16x8*)(inb + 0 * HID + kt * 32);
    XAz = SPLAT4(bin0); XAr = SPLAT4(bin1); XAh = SPLAT4(bin2);
    XAz = __builtin_amdgcn_mfma_f32_16x16x32_f16(bb[0][0], KB[0][0], XAz, 0, 0, 0);
    XAz = __builtin_amdgcn_mfma_f32_16x16x32_f16(bb[0][1], KB[0][1], XAz, 0, 0, 0);
    XAz = __builtin_amdgcn_mfma_f32_16x16x32_f16(bb[0][2], KB[0][2], XAz, 0, 0, 0);
    XAz = __builtin_amdgcn_mfma_f32_16x16x32_f16(bb[0][3], KB[0][3], XAz, 0, 0, 0);
    XAr = __builtin_amdgcn_mfma_f32_16x16x32_f16(bb[0][0], KB[1][0], XAr, 0, 0, 0);
    XAr = __builtin_amdgcn_mfma_f32_16x16x32_f16(bb[0][1], KB[1][1], XAr, 0, 0, 0);
    XAr = __builtin_amdgcn_mfma_f32_16x16x32_f16(bb[0][2], KB[1][2], XAr, 0, 0, 0);
    XAr = __builtin_amdgcn_mfma_f32_16x16x32_f16(bb[0][3], KB[1][3], XAr, 0, 0, 0);
    XAh = __builtin_amdgcn_mfma_f32_16x16x32_f16(bb[0][0], KB[2][0], XAh, 0, 0, 0);
    XAh = __builtin_amdgcn_mfma_f32_16x16x32_f16(bb[0][1], KB[2][1], XAh, 0, 0, 0);
    XAh = __builtin_amdgcn_mfma_f32_16x16x32_f16(bb[0][2], KB[2][2], XAh, 0, 0, 0);
    XAh = __builtin_amdgcn_mfma_f32_16x16x32_f16(bb[0][3], KB[2][3], XAh, 0, 0, 0);
    // prefetch X[1] -> bb[1], X[2] -> bb[0]
#pragma unroll
    for (int kt = 0; kt < 4; ++kt)
        bb[1][kt] = *(const f16x8*)(inb + (size_t)1 * HID + kt * 32);
#pragma unroll
    for (int kt = 0; kt < 4; ++kt)
        bb[0][kt] = *(const f16x8*)(inb + (size_t)2 * HID + kt * 32);

// One GRU step. P = s&1 (compile-time). Consumes XC* (xw[s]), produces XN*
// (xw[s+1]); reads H slot P, writes slot 1-P; prefetches X[s+3] -> bb[1-P].
#define GSTEP(P, XCz, XCr, XCh, XNz, XNr, XNh)                                  \
    {                                                                           \
        const int s_ = c * CHK + ts + (P);                                      \
        /* H A-frags from slot P (swizzled) */                                  \
        const f16x8 ha0 = *(const f16x8*)(hsp + (P) * 2048 + (hr[0] >> 1));     \
        const f16x8 ha1 = *(const f16x8*)(hsp + (P) * 2048 + (hr[1] >> 1));     \
        const f16x8 ha2 = *(const f16x8*)(hsp + (P) * 2048 + (hr[2] >> 1));     \
        const f16x8 ha3 = *(const f16x8*)(hsp + (P) * 2048 + (hr[3] >> 1));     \
        /* xw[s+1]: MFMA from bb[1-P] (reg-only, fills LDS-read latency) */     \
        XNz = SPLAT4(bin0); XNr = SPLAT4(bin1); XNh = SPLAT4(bin2);             \
        XNz = __builtin_amdgcn_mfma_f32_16x16x32_f16(bb[1-(P)][0], KB[0][0], XNz, 0,0,0); \
        XNz = __builtin_amdgcn_mfma_f32_16x16x32_f16(bb[1-(P)][1], KB[0][1], XNz, 0,0,0); \
        XNz = __builtin_amdgcn_mfma_f32_16x16x32_f16(bb[1-(P)][2], KB[0][2], XNz, 0,0,0); \
        XNz = __builtin_amdgcn_mfma_f32_16x16x32_f16(bb[1-(P)][3], KB[0][3], XNz, 0,0,0); \
        XNr = __builtin_amdgcn_mfma_f32_16x16x32_f16(bb[1-(P)][0], KB[1][0], XNr, 0,0,0); \
        XNr = __builtin_amdgcn_mfma_f32_16x16x32_f16(bb[1-(P)][1], KB[1][1], XNr, 0,0,0); \
        XNr = __builtin_amdgcn_mfma_f32_16x16x32_f16(bb[1-(P)][2], KB[1][2], XNr, 0,0,0); \
        XNr = __builtin_amdgcn_mfma_f32_16x16x32_f16(bb[1-(P)][3], KB[1][3], XNr, 0,0,0); \
        XNh = __builtin_amdgcn_mfma_f32_16x16x32_f16(bb[1-(P)][0], KB[2][0], XNh, 0,0,0); \
        XNh = __builtin_amdgcn_mfma_f32_16x16x32_f16(bb[1-(P)][1], KB[2][1], XNh, 0,0,0); \
        XNh = __builtin_amdgcn_mfma_f32_16x16x32_f16(bb[1-(P)][2], KB[2][2], XNh, 0,0,0); \
        XNh = __builtin_amdgcn_mfma_f32_16x16x32_f16(bb[1-(P)][3], KB[2][3], XNh, 0,0,0); \
        /* prefetch X[s+3] into bb[1-P] (just consumed) */                      \
        {   const int tl = (s_ + 3 < T) ? s_ + 3 : T - 1;                       \
            const _Float16* ib_ = inb + (size_t)tl * HID;                       \
            bb[1-(P)][0] = *(const f16x8*)(ib_);                                \
            bb[1-(P)][1] = *(const f16x8*)(ib_ + 32);                           \
            bb[1-(P)][2] = *(const f16x8*)(ib_ + 64);                           \
            bb[1-(P)][3] = *(const f16x8*)(ib_ + 96);                           \
        }                                                                       \
        /* recurrent G = H @ R + b_rec */                                       \
        f32x4 Gz = SPLAT4(brc0), Gr = SPLAT4(brc1), Gh = SPLAT4(brc2);          \
        Gz = __builtin_amdgcn_mfma_f32_16x16x32_f16(ha0, RB[0][0], Gz, 0,0,0);  \
        Gz = __builtin_amdgcn_mfma_f32_16x16x32_f16(ha1, RB[0][1], Gz, 0,0,0);  \
        Gz = __builtin_amdgcn_mfma_f32_16x16x32_f16(ha2, RB[0][2], Gz, 0,0,0);  \
        Gz = __builtin_amdgcn_mfma_f32_16x16x32_f16(ha3, RB[0][3], Gz, 0,0,0);  \
        Gr = __builtin_amdgcn_mfma_f32_16x16x32_f16(ha0, RB[1][0], Gr, 0,0,0);  \
        Gr = __builtin_amdgcn_mfma_f32_16x16x32_f16(ha1, RB[1][1], Gr, 0,0,0);  \
        Gr = __builtin_amdgcn_mfma_f32_16x16x32_f16(ha2, RB[1][2], Gr, 0,0,0);  \
        Gr = __builtin_amdgcn_mfma_f32_16x16x32_f16(ha3, RB[1][3], Gr, 0,0,0);  \
        Gh = __builtin_amdgcn_mfma_f32_16x16x32_f16(ha0, RB[2][0], Gh, 0,0,0);  \
        Gh = __builtin_amdgcn_mfma_f32_16x16x32_f16(ha1, RB[2][1], Gh, 0,0,0);  \
        Gh = __builtin_amdgcn_mfma_f32_16x16x32_f16(ha2, RB[2][2], Gh, 0,0,0);  \
        Gh = __builtin_amdgcn_mfma_f32_16x16x32_f16(ha3, RB[2][3], Gh, 0,0,0);  \
        /* gates + update + stores (4 batches) */                               \
        _Pragma("unroll")                                                       \
        for (int q = 0; q < 4; ++q) {                                           \
            const float z_  = fsigmoid(Gz[q] + (XCz)[q]);                       \
            const float r_  = fsigmoid(Gr[q] + (XCr)[q]);                       \
            const float hh_ = ftanh_(fmaf(r_, Gh[q], (XCh)[q]));                \
            const float hn_ = fmaf(z_, hold[q] - hh_, hh_);                     \
            hold[q] = hn_;                                                      \
            const _Float16 hf_ = (_Float16)hn_;                                 \
            hsp[(1-(P)) * 2048 + (hw[q] >> 1)] = hf_;                           \
            hpq[q][(size_t)s_ * HID] = hf_;                                     \
        }                                                                       \
        soft_barrier();                                                         \
    }

    // ---- main loop ----
    for (int c = 0; c < NC; ++c) {
        __syncthreads();   // drains vmcnt: h stores of prev chunk visible-ready
        if (t == 0) {
            if (layer < 2 && c > 0)
                __hip_atomic_store(myflag, c * CHK, __ATOMIC_RELEASE, __HIP_MEMORY_SCOPE_AGENT);
            if (layer > 0 && c + 1 < NC) {
                while (__hip_atomic_load(sflag, __ATOMIC_ACQUIRE, __HIP_MEMORY_SCOPE_AGENT) < (c + 2) * CHK)
                    __builtin_amdgcn_s_sleep(4);
            }
        }
        __syncthreads();

        for (int ts = 0; ts < CHK; ts += 2) {
            GSTEP(0, XAz, XAr, XAh, XBz, XBr, XBh)
            GSTEP(1, XBz, XBr, XBh, XAz, XAr, XAh)
        }
    }

    __syncthreads();
    if (t == 0 && layer < 2)
        __hip_atomic_store(myflag, T, __ATOMIC_RELEASE, __HIP_MEMORY_SCOPE_AGENT);
#undef GSTEP
}

// ---------------------------------------------------------------------------
// out_proj: out[r,:] = h_f16[r,:] @ wo + bo (fp32 out). Thread = row.
// ---------------------------------------------------------------------------
__global__ __launch_bounds__(256) void out_proj(
    const _Float16* __restrict__ Hf,  // [R,128] f16
    const float* __restrict__ wo,     // [128,5]
    const float* __restrict__ bo,     // [5]
    float*       __restrict__ out,    // [R,5]
    int R)
{
    const int r = blockIdx.x * 256 + threadIdx.x;
    if (r >= R) return;
    const f16x8* xp = (const f16x8*)(Hf + (size_t)r * HID);

    float a0 = bo[0], a1 = bo[1], a2 = bo[2], a3 = bo[3], a4 = bo[4];
#pragma unroll 4
    for (int c = 0; c < 16; ++c) {
        const f16x8 v = xp[c];
#pragma unroll
        for (int e = 0; e < 8; ++e) {
            const float xv = (float)v[e];
            const float* wp = wo + (size_t)(8 * c + e) * OUTD;
            a0 = fmaf(xv, wp[0], a0);
            a1 = fmaf(xv, wp[1], a1);
            a2 = fmaf(xv, wp[2], a2);
            a3 = fmaf(xv, wp[3], a3);
            a4 = fmaf(xv, wp[4], a4);
        }
    }
    float* op = out + (size_t)r * OUTD;
    op[0] = a0; op[1] = a1; op[2] = a2; op[3] = a3; op[4] = a4;
}

// ---------------------------------------------------------------------------
extern "C" void kernel_launch(void* const* d_in, const int* in_sizes, int n_in,
                              void* d_out, int out_size, void* d_ws, size_t ws_size,
                              hipStream_t stream) {
    const float* x   = (const float*)d_in[0];
    const float* k0  = (const float*)d_in[1];
    const float* rk0 = (const float*)d_in[2];
    const float* b0  = (const float*)d_in[3];
    const float* k1  = (const float*)d_in[4];
    const float* rk1 = (const float*)d_in[5];
    const float* b1  = (const float*)d_in[6];
    const float* k2  = (const float*)d_in[7];
    const float* rk2 = (const float*)d_in[8];
    const float* b2  = (const float*)d_in[9];
    const float* wo  = (const float*)d_in[10];
    const float* bo  = (const float*)d_in[11];
    float* out = (float*)d_out;

    const int BT = in_sizes[0] / HID;   // 64*2048 = 131072 rows
    const int B  = 64;
    const int T  = BT / B;              // 2048

    // ws: 3 f16 h-planes + x16 f16 plane + flags
    const size_t plane = (size_t)BT * HID * sizeof(_Float16);   // 33.55MB
    _Float16* hpl0 = (_Float16*)d_ws;
    _Float16* hpl1 = (_Float16*)((char*)d_ws + plane);
    _Float16* hpl2 = (_Float16*)((char*)d_ws + 2 * plane);
    _Float16* x16  = (_Float16*)((char*)d_ws + 3 * plane);
    int*      flags = (int*)((char*)d_ws + 4 * plane);

    const int n8 = BT * HID / 8;        // 2.097M f16x8 groups

    zero_flags<<<1, 64, 0, stream>>>(flags);
    xcvt      <<<(n8 + 255) / 256, 256, 0, stream>>>(x, x16, n8);
    gru12     <<<12, 512, 0, stream>>>(x16, k0, k1, k2, rk0, rk1, rk2,
                                       b0, b1, b2, hpl0, hpl1, hpl2, flags, T);
    out_proj  <<<(BT + 255) / 256, 256, 0, stream>>>(hpl2, wo, bo, out, BT);
}

// Round 8
// 2342.570 us; speedup vs baseline: 1.3168x; 1.1234x over previous
//
#include <hip/hip_runtime.h>
#include <hip/hip_bf16.h>
#include <hip/hip_fp16.h>

// ---------------------------------------------------------------------------
// 3-layer GRU (Keras v2, reset_after=True), B=64 T=2048 F=H=128, OUT=5.
// Round 14 = Round 13 resubmit (container infra failure, no data; re-audited
// deadlock/OOB — one latent pointer clamp added).
// Design: MFMA recurrence (r12 core, verified correct) + xw GEMM offloaded
// to producer WGs + chunk-granular h flush.
//   r12 diagnosis: 192 MFMA/CU/step = 931cy pipe floor on 12 CUs (26% util
//   measured); per-step 2B global h-scatter stores poison the in-order vmcnt
//   FIFO ahead of prefetch loads; ds_write_b16 h-scatter 4-way bank conflict
//   (3.1M). Fixes:
//   1) 48 proj WGs (4 per rec WG) compute xw = X@K + b_in by MFMA and store
//      C-FRAGMENT-layout f32x4 into an 18.9MB ring; rec reads 3 dwordx4/step,
//      prefetch distance 4 (XW[4] slots, ts%4 static). Rec MFMA/CU/step: 96.
//   2) h history in regs (f16x4 hhv[16], full unroll), flushed per chunk via
//      32KB LDS transpose -> coalesced dwordx4 h-plane writes. Rec per-step
//      vmcnt FIFO = 3 loads only.
//   3) H dbuf swizzle ^(row<<4) full 4 bits (r12's &7 collided lg-pairs).
//   Protocol: hflag[12] rec progress (publish c*CHK at boundary, T at end;
//   doubles as ring backpressure), pflag[48] proj progress. Rec boundary
//   waits pflag >= min((c+2)CHK, T); proj waits hflag(l-1) >= (cc+1)CHK
//   (input) and hflag(l) >= (cc-3)CHK (ring, RING=4). Deadlock-audited
//   acyclic; 60 WGs all co-resident.
// ws: 3 f16 h-planes (33.55MB) + ring 18.87MB + 60 flags.
// ---------------------------------------------------------------------------

#define HID   128
#define H3    384
#define OUTD  5
#define CHK   16
#define RING  4
#define NRECWG 12
#define TS_F32   6144       // 8 waves * 3 gates * 64 lanes * 4 f32 per step
#define SLOT_F32 98304      // CHK * TS_F32
#define GRP_F32  393216     // RING * SLOT_F32

typedef _Float16 f16x4 __attribute__((ext_vector_type(4)));
typedef _Float16 f16x8 __attribute__((ext_vector_type(8)));
typedef float    f32x4 __attribute__((ext_vector_type(4)));

#define SPLAT4(v) ((f32x4){(v), (v), (v), (v)})
#define MFMA(a, b, c) __builtin_amdgcn_mfma_f32_16x16x32_f16((a), (b), (c), 0, 0, 0)

__device__ __forceinline__ float fexp2(float x) {
#if __has_builtin(__builtin_amdgcn_exp2f)
    return __builtin_amdgcn_exp2f(x);
#else
    return exp2f(x);
#endif
}

__device__ __forceinline__ float frcp(float x) {
#if __has_builtin(__builtin_amdgcn_rcpf)
    return __builtin_amdgcn_rcpf(x);
#else
    return 1.f / x;
#endif
}

__device__ __forceinline__ float fsigmoid(float x) {
    return frcp(1.f + fexp2(x * -1.4426950408889634f));
}

__device__ __forceinline__ float ftanh_(float x) {
    return fmaf(-2.f, frcp(1.f + fexp2(x * 2.8853900817779268f)), 1.f);
}

// barrier that does NOT drain vmcnt (unlike __syncthreads): LDS handoff only.
__device__ __forceinline__ void soft_barrier() {
    asm volatile("s_waitcnt lgkmcnt(0)\n\ts_barrier" ::: "memory");
}

// ---------------------------------------------------------------------------
__global__ void zero_flags(int* f) {
    if (threadIdx.x < 60) f[threadIdx.x] = 0;
}

// ---------------------------------------------------------------------------
// gru13: 60 WGs, 512 thr (8 waves).
//  blk < 12 : REC (layer=blk>>2, group g=blk&3, batches 16g..16g+15).
//    Per step: 4 ds_read_b128 (H frags, ^(row<<4) swz dbuf) + 12 MFMA (G =
//    H@R + b_rec) + gates (in-lane) + 4 ds_write_b16 (H dbuf) + hhv reg
//    append + 3 dwordx4 xw loads (distance-4 prefetch) + soft_barrier.
//    Per chunk: LDS-transpose flush of hhv -> coalesced h-plane writes.
//  blk >= 12: PROJ (pb=blk-12: layer=pb>>4, g=(pb>>2)&3, sub=pb&3).
//    Per chunk: 4 steps (sub*4..+3): A-frags global->reg (x f32 cvt for l0,
//    h-plane f16 else), 12 MFMA (xw = X@K + b_in), 3 dwordx4 ring stores in
//    C-fragment layout; release pflag.
// ---------------------------------------------------------------------------
__global__ __launch_bounds__(512, 1) void gru13(
    const float* __restrict__ x,                         // [64,T,128] fp32
    const float* __restrict__ k0, const float* __restrict__ k1, const float* __restrict__ k2,
    const float* __restrict__ rk0, const float* __restrict__ rk1, const float* __restrict__ rk2,
    const float* __restrict__ b0, const float* __restrict__ b1, const float* __restrict__ b2,
    _Float16* __restrict__ hpl0, _Float16* __restrict__ hpl1, _Float16* __restrict__ hpl2,
    float* __restrict__ xwr,                             // ring, C-frag layout
    int* flags, int T)
{
    const int blk = blockIdx.x;
    const int t   = threadIdx.x;      // 0..511
    const int NC  = T / CHK;
    const int w   = t >> 6;           // wave 0..7 (unit-block)
    const int l   = t & 63;
    const int li  = l & 15;
    const int lg  = l >> 4;

    __shared__ __align__(16) char lds_raw[40960];        // 8KB Hs + 32KB flush

    if (blk < NRECWG) {
        // =================== RECURRENT ROLE ====================
        const int layer = blk >> 2;
        const int g     = blk & 3;
        const int bg    = g * 16;

        _Float16* hsp = (_Float16*)lds_raw;              // [2][2048] H dbuf
        _Float16* fb  = (_Float16*)(lds_raw + 8192);     // flush [8][16][128]

        const float* Rw = (layer == 0) ? rk0 : (layer == 1) ? rk1 : rk2;
        const float* Bs = (layer == 0) ? b0  : (layer == 1) ? b1  : b2;
        _Float16* hout = (layer == 0) ? hpl0 : (layer == 1) ? hpl1 : hpl2;

        // B-frags of R: 3 gates x 4 k-tiles (48 VGPR)
        f16x8 RB[3][4];
#pragma unroll
        for (int gi = 0; gi < 3; ++gi) {
            const int col = 16 * w + 128 * gi + li;
            const float* Rc = Rw + col;
#pragma unroll
            for (int kt = 0; kt < 4; ++kt) {
                f16x8 rv;
#pragma unroll
                for (int e = 0; e < 8; ++e) {
                    const int k = kt * 32 + lg * 8 + e;
                    rv[e] = (_Float16)Rc[(size_t)k * H3];
                }
                RB[gi][kt] = rv;
            }
        }
        const int uz = 16 * w + li;
        const float brc0 = Bs[H3 + uz];
        const float brc1 = Bs[H3 + 128 + uz];
        const float brc2 = Bs[H3 + 256 + uz];

        // LDS addresses (bytes), swizzle ^(row<<4), row = batch index
        int hr[4], hw2[4];
#pragma unroll
        for (int kt = 0; kt < 4; ++kt)
            hr[kt] = (li * 256 + kt * 64 + lg * 16) ^ (li << 4);
#pragma unroll
        for (int q = 0; q < 4; ++q) {
            const int b = lg * 4 + q;
            hw2[q] = (b * 256 + uz * 2) ^ (b << 4);
        }

        const float* ringb = xwr + (size_t)blk * GRP_F32 + (w * 3) * 256 + l * 4;
        int* hflag = flags + blk;
        int* pf    = flags + NRECWG + blk * 4;

        // zero H dbuf (both slots, 8KB)
        ((float4*)hsp)[t] = float4{0.f, 0.f, 0.f, 0.f};

        f32x4 XWz[4], XWr[4], XWh[4];
        f32x4 hold = SPLAT4(0.f);
        f16x4 hhv[16];

// chunk flush: hhv regs -> LDS transpose (2 halves of 8 steps) -> coalesced
#define FLUSHC(CC)                                                              \
    _Pragma("unroll")                                                           \
    for (int hf2 = 0; hf2 < 2; ++hf2) {                                         \
        _Pragma("unroll")                                                       \
        for (int tsq = 0; tsq < 8; ++tsq) {                                     \
            _Pragma("unroll")                                                   \
            for (int q = 0; q < 4; ++q)                                         \
                fb[(tsq * 16 + lg * 4 + q) * 128 + uz] = hhv[hf2 * 8 + tsq][q]; \
        }                                                                       \
        soft_barrier();                                                         \
        {                                                                       \
            const int ts8 = t >> 6;                                             \
            const int fbb = (t >> 2) & 15;                                      \
            const int q4  = t & 3;                                              \
            const _Float16* sp_ = fb + (ts8 * 16 + fbb) * 128 + q4 * 32;        \
            _Float16* dp_ = hout + ((size_t)(bg + fbb) * T                      \
                            + ((CC) * CHK + hf2 * 8 + ts8)) * HID + q4 * 32;    \
            _Pragma("unroll")                                                   \
            for (int e = 0; e < 4; ++e)                                         \
                ((f16x8*)dp_)[e] = ((const f16x8*)sp_)[e];                      \
        }                                                                       \
        soft_barrier();                                                         \
    }

// one GRU step, TS literal 0..15
#define GSTEP(TS)                                                               \
    {                                                                           \
        const int P_ = (TS) & 1;                                                \
        const int M_ = (TS) & 3;                                                \
        const f16x8 ha0 = *(const f16x8*)(hsp + P_ * 2048 + (hr[0] >> 1));      \
        const f16x8 ha1 = *(const f16x8*)(hsp + P_ * 2048 + (hr[1] >> 1));      \
        const f16x8 ha2 = *(const f16x8*)(hsp + P_ * 2048 + (hr[2] >> 1));      \
        const f16x8 ha3 = *(const f16x8*)(hsp + P_ * 2048 + (hr[3] >> 1));      \
        f32x4 Gz = SPLAT4(brc0), Gr = SPLAT4(brc1), Gh = SPLAT4(brc2);          \
        Gz = MFMA(ha0, RB[0][0], Gz); Gz = MFMA(ha1, RB[0][1], Gz);             \
        Gz = MFMA(ha2, RB[0][2], Gz); Gz = MFMA(ha3, RB[0][3], Gz);             \
        Gr = MFMA(ha0, RB[1][0], Gr); Gr = MFMA(ha1, RB[1][1], Gr);             \
        Gr = MFMA(ha2, RB[1][2], Gr); Gr = MFMA(ha3, RB[1][3], Gr);             \
        Gh = MFMA(ha0, RB[2][0], Gh); Gh = MFMA(ha1, RB[2][1], Gh);             \
        Gh = MFMA(ha2, RB[2][2], Gh); Gh = MFMA(ha3, RB[2][3], Gh);             \
        _Pragma("unroll")                                                       \
        for (int q = 0; q < 4; ++q) {                                           \
            const float z_  = fsigmoid(Gz[q] + XWz[M_][q]);                     \
            const float r_  = fsigmoid(Gr[q] + XWr[M_][q]);                     \
            const float hh_ = ftanh_(fmaf(r_, Gh[q], XWh[M_][q]));              \
            const float hn_ = fmaf(z_, hold[q] - hh_, hh_);                     \
            hold[q] = hn_;                                                      \
            const _Float16 hf_ = (_Float16)hn_;                                 \
            hsp[(P_ ^ 1) * 2048 + (hw2[q] >> 1)] = hf_;                         \
            hhv[TS][q] = hf_;                                                   \
        }                                                                       \
        {                                                                       \
            int s4_ = c * CHK + (TS) + 4;                                       \
            if (s4_ > T - 1) s4_ = T - 1;                                       \
            const float* p_ = ringb + (size_t)((s4_ >> 4) & (RING - 1)) * SLOT_F32 \
                              + (s4_ & 15) * TS_F32;                            \
            XWz[M_] = *(const f32x4*)(p_);                                      \
            XWr[M_] = *(const f32x4*)(p_ + 256);                                \
            XWh[M_] = *(const f32x4*)(p_ + 512);                                \
        }                                                                       \
        soft_barrier();                                                         \
    }

        for (int c = 0; c < NC; ++c) {
            if (c > 0) { FLUSHC(c - 1) }
            __syncthreads();   // drains flush stores (vmcnt) + everything
            if (t == 0) {
                if (c > 0)
                    __hip_atomic_store(hflag, c * CHK, __ATOMIC_RELEASE, __HIP_MEMORY_SCOPE_AGENT);
                int wv = (c + 2) * CHK; if (wv > T) wv = T;
#pragma unroll
                for (int s = 0; s < 4; ++s) {
                    while (__hip_atomic_load(pf + s, __ATOMIC_ACQUIRE, __HIP_MEMORY_SCOPE_AGENT) < wv)
                        __builtin_amdgcn_s_sleep(4);
                }
            }
            __syncthreads();
            if (c == 0) {
#pragma unroll
                for (int s = 0; s < 4; ++s) {
                    const float* p_ = ringb + s * TS_F32;
                    XWz[s] = *(const f32x4*)(p_);
                    XWr[s] = *(const f32x4*)(p_ + 256);
                    XWh[s] = *(const f32x4*)(p_ + 512);
                }
            }
            GSTEP(0)  GSTEP(1)  GSTEP(2)  GSTEP(3)
            GSTEP(4)  GSTEP(5)  GSTEP(6)  GSTEP(7)
            GSTEP(8)  GSTEP(9)  GSTEP(10) GSTEP(11)
            GSTEP(12) GSTEP(13) GSTEP(14) GSTEP(15)
        }
        FLUSHC(NC - 1)
        __syncthreads();
        if (t == 0)
            __hip_atomic_store(hflag, T, __ATOMIC_RELEASE, __HIP_MEMORY_SCOPE_AGENT);
#undef GSTEP
#undef FLUSHC

    } else {
        // =================== PROJECTION ROLE ====================
        const int pb    = blk - NRECWG;
        const int layer = pb >> 4;
        const int g     = (pb >> 2) & 3;
        const int sub   = pb & 3;
        const int bg    = g * 16;
        const int lg4   = layer * 4 + g;

        const float* Kw = (layer == 0) ? k0 : (layer == 1) ? k1 : k2;
        const float* Bs = (layer == 0) ? b0 : (layer == 1) ? b1 : b2;

        f16x8 KB[3][4];
#pragma unroll
        for (int gi = 0; gi < 3; ++gi) {
            const int col = 16 * w + 128 * gi + li;
            const float* Kc = Kw + col;
#pragma unroll
            for (int kt = 0; kt < 4; ++kt) {
                f16x8 kv;
#pragma unroll
                for (int e = 0; e < 8; ++e) {
                    const int k = kt * 32 + lg * 8 + e;
                    kv[e] = (_Float16)Kc[(size_t)k * H3];
                }
                KB[gi][kt] = kv;
            }
        }
        const int uz = 16 * w + li;
        const float bin0 = Bs[uz];
        const float bin1 = Bs[128 + uz];
        const float bin2 = Bs[256 + uz];

        float* ringp = xwr + (size_t)lg4 * GRP_F32 + (w * 3) * 256 + l * 4;
        int* myp  = flags + NRECWG + lg4 * 4 + sub;
        int* hfin = flags + ((layer > 0 ? layer - 1 : 0) * 4 + g);   // used only if layer>0
        int* hown = flags + lg4;

        const float*    xfb = x + ((size_t)(bg + li) * T) * HID + lg * 8;
        const _Float16* hfb = ((layer == 1) ? hpl0 : hpl1) + ((size_t)(bg + li) * T) * HID + lg * 8;

        for (int cc = 0; cc < NC; ++cc) {
            if (t == 0) {
                if (layer > 0) {
                    while (__hip_atomic_load(hfin, __ATOMIC_ACQUIRE, __HIP_MEMORY_SCOPE_AGENT) < (cc + 1) * CHK)
                        __builtin_amdgcn_s_sleep(4);
                }
                if (cc >= RING) {
                    while (__hip_atomic_load(hown, __ATOMIC_ACQUIRE, __HIP_MEMORY_SCOPE_AGENT) < (cc - (RING - 1)) * CHK)
                        __builtin_amdgcn_s_sleep(4);
                }
            }
            __syncthreads();

            // A-frags for this sub's 4 steps
            f16x8 af[4][4];
#pragma unroll
            for (int st = 0; st < 4; ++st) {
                const int tstep = cc * CHK + sub * 4 + st;
                if (layer == 0) {
#pragma unroll
                    for (int kt = 0; kt < 4; ++kt) {
                        const float4 a  = *(const float4*)(xfb + (size_t)tstep * HID + kt * 32);
                        const float4 bq = *(const float4*)(xfb + (size_t)tstep * HID + kt * 32 + 4);
                        f16x8 v;
                        v[0] = (_Float16)a.x;  v[1] = (_Float16)a.y;
                        v[2] = (_Float16)a.z;  v[3] = (_Float16)a.w;
                        v[4] = (_Float16)bq.x; v[5] = (_Float16)bq.y;
                        v[6] = (_Float16)bq.z; v[7] = (_Float16)bq.w;
                        af[st][kt] = v;
                    }
                } else {
#pragma unroll
                    for (int kt = 0; kt < 4; ++kt)
                        af[st][kt] = *(const f16x8*)(hfb + (size_t)tstep * HID + kt * 32);
                }
            }
#pragma unroll
            for (int st = 0; st < 4; ++st) {
                f32x4 Cz = SPLAT4(bin0), Cr = SPLAT4(bin1), Ch = SPLAT4(bin2);
                Cz = MFMA(af[st][0], KB[0][0], Cz); Cz = MFMA(af[st][1], KB[0][1], Cz);
                Cz = MFMA(af[st][2], KB[0][2], Cz); Cz = MFMA(af[st][3], KB[0][3], Cz);
                Cr = MFMA(af[st][0], KB[1][0], Cr); Cr = MFMA(af[st][1], KB[1][1], Cr);
                Cr = MFMA(af[st][2], KB[1][2], Cr); Cr = MFMA(af[st][3], KB[1][3], Cr);
                Ch = MFMA(af[st][0], KB[2][0], Ch); Ch = MFMA(af[st][1], KB[2][1], Ch);
                Ch = MFMA(af[st][2], KB[2][2], Ch); Ch = MFMA(af[st][3], KB[2][3], Ch);
                float* d = ringp + (size_t)(cc & (RING - 1)) * SLOT_F32
                           + (sub * 4 + st) * TS_F32;
                *(f32x4*)(d)       = Cz;
                *(f32x4*)(d + 256) = Cr;
                *(f32x4*)(d + 512) = Ch;
            }
            __syncthreads();   // drain ring stores before release
            if (t == 0)
                __hip_atomic_store(myp, (cc + 1) * CHK, __ATOMIC_RELEASE, __HIP_MEMORY_SCOPE_AGENT);
        }
    }
}

// ---------------------------------------------------------------------------
// out_proj: out[r,:] = h_f16[r,:] @ wo + bo (fp32 out). Thread = row.
// ---------------------------------------------------------------------------
__global__ __launch_bounds__(256) void out_proj(
    const _Float16* __restrict__ Hf,  // [R,128] f16
    const float* __restrict__ wo,     // [128,5]
    const float* __restrict__ bo,     // [5]
    float*       __restrict__ out,    // [R,5]
    int R)
{
    const int r = blockIdx.x * 256 + threadIdx.x;
    if (r >= R) return;
    const f16x8* xp = (const f16x8*)(Hf + (size_t)r * HID);

    float a0 = bo[0], a1 = bo[1], a2 = bo[2], a3 = bo[3], a4 = bo[4];
#pragma unroll 4
    for (int c = 0; c < 16; ++c) {
        const f16x8 v = xp[c];
#pragma unroll
        for (int e = 0; e < 8; ++e) {
            const float xv = (float)v[e];
            const float* wp = wo + (size_t)(8 * c + e) * OUTD;
            a0 = fmaf(xv, wp[0], a0);
            a1 = fmaf(xv, wp[1], a1);
            a2 = fmaf(xv, wp[2], a2);
            a3 = fmaf(xv, wp[3], a3);
            a4 = fmaf(xv, wp[4], a4);
        }
    }
    float* op = out + (size_t)r * OUTD;
    op[0] = a0; op[1] = a1; op[2] = a2; op[3] = a3; op[4] = a4;
}

// ---------------------------------------------------------------------------
extern "C" void kernel_launch(void* const* d_in, const int* in_sizes, int n_in,
                              void* d_out, int out_size, void* d_ws, size_t ws_size,
                              hipStream_t stream) {
    const float* x   = (const float*)d_in[0];
    const float* k0  = (const float*)d_in[1];
    const float* rk0 = (const float*)d_in[2];
    const float* b0  = (const float*)d_in[3];
    const float* k1  = (const float*)d_in[4];
    const float* rk1 = (const float*)d_in[5];
    const float* b1  = (const float*)d_in[6];
    const float* k2  = (const float*)d_in[7];
    const float* rk2 = (const float*)d_in[8];
    const float* b2  = (const float*)d_in[9];
    const float* wo  = (const float*)d_in[10];
    const float* bo  = (const float*)d_in[11];
    float* out = (float*)d_out;

    const int BT = in_sizes[0] / HID;   // 64*2048 = 131072 rows
    const int B  = 64;
    const int T  = BT / B;              // 2048

    // ws: 3 f16 h-planes + f32 xw ring (C-frag layout) + flags
    const size_t plane = (size_t)BT * HID * sizeof(_Float16);        // 33.55MB
    const size_t ringb = (size_t)NRECWG * GRP_F32 * sizeof(float);   // 18.87MB
    _Float16* hpl0 = (_Float16*)d_ws;
    _Float16* hpl1 = (_Float16*)((char*)d_ws + plane);
    _Float16* hpl2 = (_Float16*)((char*)d_ws + 2 * plane);
    float*    xwr  = (float*)((char*)d_ws + 3 * plane);
    int*      flags = (int*)((char*)d_ws + 3 * plane + ringb);

    zero_flags<<<1, 64, 0, stream>>>(flags);
    gru13     <<<60, 512, 0, stream>>>(x, k0, k1, k2, rk0, rk1, rk2,
                                       b0, b1, b2, hpl0, hpl1, hpl2, xwr, flags, T);
    out_proj  <<<(BT + 255) / 256, 256, 0, stream>>>(hpl2, wo, bo, out, BT);
}

// Round 9
// 1751.958 us; speedup vs baseline: 1.7607x; 1.3371x over previous
//
#include <hip/hip_runtime.h>
#include <hip/hip_bf16.h>
#include <hip/hip_fp16.h>

// ---------------------------------------------------------------------------
// 3-layer GRU (Keras v2, reset_after=True), B=64 T=2048 F=H=128, OUT=5.
// Round 15: RESTORE r6 (session best, 1752us measured) after three structural
// families all measured worse:
//   r7  wave-split producer/consumer (shared WG barrier -> lockstep)   2038
//   r8  batch-pair in-thread ILP (halves CUs)                          2941
//   r9  global f32 ring, 1:3 producers (4B scatter, 1.28GB writes)     4306
//   r10 chunk-boundary proj block (issue still in rec stream)          1910
//   r11 1:1 co-resident producers, coalesced ring (wbl2 storms)        3085
//   r12 MFMA recurrence, 12 WGs (2 GEMMs/CU/step = 931cy pipe floor)   2632
//   r14 MFMA + offloaded xw + chunk h-flush (85% stall, flag latency)  2342
// r6's balance: layer-pipelined persistent kernel (192 WGs on 192 CUs),
// inline input projection per step acting as in-stream latency filler,
// ONE lgkm-only soft_barrier per step, chunked (CHK=16) staging + agent-
// scope release/acquire layer handoff, zero auxiliary global traffic.
// ws: 3 h-planes f16 32MB each + flags.
// ---------------------------------------------------------------------------

#define HID   128
#define H3    384
#define OUTD  5
#define CHK   16            // steps per chunk (publish/poll granularity)

typedef _Float16 f16x2 __attribute__((ext_vector_type(2)));
typedef _Float16 f16x8 __attribute__((ext_vector_type(8)));

__device__ __forceinline__ float fdot2(f16x2 a, f16x2 b, float c) {
#if __has_builtin(__builtin_amdgcn_fdot2)
    return __builtin_amdgcn_fdot2(a, b, c, false);   // v_dot2_f32_f16
#else
    return fmaf((float)a.x, (float)b.x, fmaf((float)a.y, (float)b.y, c));
#endif
}

__device__ __forceinline__ float fexp2(float x) {
#if __has_builtin(__builtin_amdgcn_exp2f)
    return __builtin_amdgcn_exp2f(x);
#else
    return exp2f(x);
#endif
}

__device__ __forceinline__ float frcp(float x) {
#if __has_builtin(__builtin_amdgcn_rcpf)
    return __builtin_amdgcn_rcpf(x);
#else
    return 1.f / x;
#endif
}

// sigmoid(x) = 1/(1+exp(-x)); saturates correctly at +-inf.
__device__ __forceinline__ float fsigmoid(float x) {
    return frcp(1.f + fexp2(x * -1.4426950408889634f));
}

// tanh(x) = 1 - 2/(1+exp(2x)); saturates correctly at +-inf.
__device__ __forceinline__ float ftanh_(float x) {
    return fmaf(-2.f, frcp(1.f + fexp2(x * 2.8853900817779268f)), 1.f);
}

// barrier that does NOT drain vmcnt (unlike __syncthreads): LDS handoff only.
__device__ __forceinline__ void soft_barrier() {
    asm volatile("s_waitcnt lgkmcnt(0)\n\ts_barrier" ::: "memory");
}

// butterfly sum over the kh quad (lanes xor 1, xor 2) on the VALU pipe
__device__ __forceinline__ float quad_sum(float x) {
#if __has_builtin(__builtin_amdgcn_mov_dpp)
    int i1 = __builtin_amdgcn_mov_dpp(__float_as_int(x), 0xB1, 0xF, 0xF, true); // [1,0,3,2]
    x += __int_as_float(i1);
    int i2 = __builtin_amdgcn_mov_dpp(__float_as_int(x), 0x4E, 0xF, 0xF, true); // [2,3,0,1]
    x += __int_as_float(i2);
#else
    x += __shfl_xor(x, 1);
    x += __shfl_xor(x, 2);
#endif
    return x;
}

// ---------------------------------------------------------------------------
__global__ void zero_flags(int* f) {
    if (threadIdx.x < 192) f[threadIdx.x] = 0;
}

// ---------------------------------------------------------------------------
// gru_pipe: 192 WGs = 3 layers x 64 batches, 512 thr (8 waves, 2/SIMD).
// Thread (j = t>>2, kh = t&3): unit j, k-quarter kh. Per step:
//   recurrent dot (48 fdot2, 16-deep) from LDS h double-buffer -> DPP reduce
//   -> gates -> h update -> LDS+global store; inline input projection for
//   step t+1 (48 fdot2 from staged input row, independent -> fills bubbles).
// ---------------------------------------------------------------------------
__global__ __launch_bounds__(512, 2) void gru_pipe(
    const float* __restrict__ x,                         // [64,T,128] fp32
    const float* __restrict__ k0, const float* __restrict__ k1, const float* __restrict__ k2,
    const float* __restrict__ rk0, const float* __restrict__ rk1, const float* __restrict__ rk2,
    const float* __restrict__ b0, const float* __restrict__ b1, const float* __restrict__ b2,
    _Float16* __restrict__ hpl0, _Float16* __restrict__ hpl1, _Float16* __restrict__ hpl2,
    int* flags, int T)
{
    const int blk   = blockIdx.x;
    const int layer = blk >> 6;       // 0..2
    const int b     = blk & 63;       // batch
    const int t     = threadIdx.x;    // 0..511
    const int j     = t >> 2;         // unit 0..127
    const int kh    = t & 3;          // k-quarter
    const int k0i   = kh * 32;
    const int NC    = T / CHK;        // 128 chunks

    const float* Kw = (layer == 0) ? k0  : (layer == 1) ? k1  : k2;
    const float* Rw = (layer == 0) ? rk0 : (layer == 1) ? rk1 : rk2;
    const float* Bs = (layer == 0) ? b0  : (layer == 1) ? b1  : b2;
    const _Float16* hin = (layer == 1) ? hpl0 : hpl1;    // unused for layer 0
    _Float16* hout = (layer == 0) ? hpl0 : (layer == 1) ? hpl1 : hpl2;

    __shared__ __align__(16) _Float16 hb[2][HID];        // own-state dbuf
    __shared__ __align__(16) _Float16 ins[2][CHK][HID];  // staged input rows

    // resident weights: recurrent + input, 3 gates x 16 f16x2 each = 96 VGPRs
    f16x2 wzR[16], wrR[16], whR[16], wzK[16], wrK[16], whK[16];
#pragma unroll
    for (int p = 0; p < 16; ++p) {
        const int k = k0i + 2 * p;
        const float* r0p = Rw + (size_t)k * H3;
        const float* r1p = Rw + (size_t)(k + 1) * H3;
        const float* k0p = Kw + (size_t)k * H3;
        const float* k1p = Kw + (size_t)(k + 1) * H3;
        f16x2 a;
        a.x = (_Float16)r0p[j];       a.y = (_Float16)r1p[j];       wzR[p] = a;
        a.x = (_Float16)r0p[j + 128]; a.y = (_Float16)r1p[j + 128]; wrR[p] = a;
        a.x = (_Float16)r0p[j + 256]; a.y = (_Float16)r1p[j + 256]; whR[p] = a;
        a.x = (_Float16)k0p[j];       a.y = (_Float16)k1p[j];       wzK[p] = a;
        a.x = (_Float16)k0p[j + 128]; a.y = (_Float16)k1p[j + 128]; wrK[p] = a;
        a.x = (_Float16)k0p[j + 256]; a.y = (_Float16)k1p[j + 256]; whK[p] = a;
    }
    const float bzK = Bs[j]       + Bs[384 + j];         // b_in(z)+b_rec(z)
    const float brK = Bs[128 + j] + Bs[384 + 128 + j];   // b_in(r)+b_rec(r)
    const float bhK = Bs[256 + j];                       // b_in(h)
    const float bhR = Bs[384 + 256 + j];                 // b_rec(h) (inside r*)

    int* myflag = flags + layer * 64 + b;
    int* sflag  = flags + (layer - 1) * 64 + b;

    const float*    xb  = x    + (size_t)b * T * HID;
    const _Float16* hib = hin  + (size_t)b * T * HID;
    _Float16*       hob = hout + (size_t)b * T * HID;

    // ---- staging helpers: chunk = CHK rows x 128 f16 = 1024 f16x2 dwords ----
    // thread handles 2 dwords: d = t + 512*i -> row = d>>6, col2 = d&63.
    f16x2 sreg[2];
    auto stage_load = [&](int cc) {
#pragma unroll
        for (int i = 0; i < 2; ++i) {
            const int d  = t + 512 * i;
            const int rw = d >> 6;
            const int c2 = d & 63;
            const size_t off = (size_t)(cc * CHK + rw) * HID + 2 * c2;
            if (layer == 0) {
                const float2 v = *(const float2*)(xb + off);
                f16x2 o; o.x = (_Float16)v.x; o.y = (_Float16)v.y;
                sreg[i] = o;
            } else {
                sreg[i] = *(const f16x2*)(hib + off);
            }
        }
    };
    auto stage_write = [&](int cc) {
        const int slot = cc & 1;
#pragma unroll
        for (int i = 0; i < 2; ++i) {
            const int d  = t + 512 * i;
            const int rw = d >> 6;
            const int c2 = d & 63;
            *(f16x2*)(&ins[slot][rw][2 * c2]) = sreg[i];
        }
    };

    if (t < HID) { hb[0][t] = (_Float16)0.f; hb[1][t] = (_Float16)0.f; }

    // ---- prologue: chunk 0 staged + proj[0] ----
    if (layer > 0 && t == 0) {
        while (__hip_atomic_load(sflag, __ATOMIC_ACQUIRE, __HIP_MEMORY_SCOPE_AGENT) < CHK)
            __builtin_amdgcn_s_sleep(4);
    }
    __syncthreads();
    stage_load(0);
    stage_write(0);      // vmcnt wait here (prologue only)
    __syncthreads();

    float xz, xr, xh;
    {
        const f16x8* ip = (const f16x8*)(&ins[0][0][k0i]);
        float pz = 0.f, pr = 0.f, ph = 0.f;
#pragma unroll
        for (int i = 0; i < 4; ++i) {
            union { f16x8 v; f16x2 p[4]; } u;
            u.v = ip[i];
#pragma unroll
            for (int q = 0; q < 4; ++q) {
                pz = fdot2(u.p[q], wzK[4 * i + q], pz);
                pr = fdot2(u.p[q], wrK[4 * i + q], pr);
                ph = fdot2(u.p[q], whK[4 * i + q], ph);
            }
        }
        xz = quad_sum(pz) + bzK;
        xr = quad_sum(pr) + brK;
        xh = quad_sum(ph) + bhK;
    }

    float h_old = 0.f;

    // ---- main loop over chunks ----
    for (int c = 0; c < NC; ++c) {
        __syncthreads();   // drains vm+lgkm (h stores of prev chunk complete)
        if (t == 0) {
            if (layer < 2 && c > 0)
                __hip_atomic_store(myflag, c * CHK, __ATOMIC_RELEASE, __HIP_MEMORY_SCOPE_AGENT);
            if (layer > 0 && c + 1 < NC) {
                while (__hip_atomic_load(sflag, __ATOMIC_ACQUIRE, __HIP_MEMORY_SCOPE_AGENT) < (c + 2) * CHK)
                    __builtin_amdgcn_s_sleep(4);
            }
        }
        __syncthreads();
        if (c + 1 < NC) stage_load(c + 1);   // loads in flight ~8 steps before ds_write

#pragma unroll 2
        for (int ts = 0; ts < CHK; ++ts) {
            const int tstep = c * CHK + ts;
            const int rbuf  = ts & 1;

            // recurrent dot from own h state
            const f16x8* hp = (const f16x8*)(&hb[rbuf][k0i]);
            float sz = 0.f, sr = 0.f, sh = 0.f;
#pragma unroll
            for (int i = 0; i < 4; ++i) {
                union { f16x8 v; f16x2 p[4]; } u;
                u.v = hp[i];
#pragma unroll
                for (int q = 0; q < 4; ++q) {
                    sz = fdot2(u.p[q], wzR[4 * i + q], sz);
                    sr = fdot2(u.p[q], wrR[4 * i + q], sr);
                    sh = fdot2(u.p[q], whR[4 * i + q], sh);
                }
            }
            sz = quad_sum(sz); sr = quad_sum(sr); sh = quad_sum(sh);

            const float z  = fsigmoid(xz + sz);
            const float r  = fsigmoid(xr + sr);
            const float hh = ftanh_(xh + (sh + bhR) * r);
            const float hn = fmaf(z, h_old - hh, hh);
            h_old = hn;

            if (kh == 0) {
                hb[rbuf ^ 1][j] = (_Float16)hn;
                hob[(size_t)tstep * HID + j] = (_Float16)hn;
            }

            if (ts == 7 && c + 1 < NC) stage_write(c + 1);  // vmcnt hidden (~8 steps old)

            // inline input projection for step t+1 (independent work)
            if (tstep + 1 < T) {
                const int tn = tstep + 1;
                const f16x8* ip = (const f16x8*)(&ins[(tn >> 4) & 1][tn & 15][k0i]);
                float pz = 0.f, pr = 0.f, ph = 0.f;
#pragma unroll
                for (int i = 0; i < 4; ++i) {
                    union { f16x8 v; f16x2 p[4]; } u;
                    u.v = ip[i];
#pragma unroll
                    for (int q = 0; q < 4; ++q) {
                        pz = fdot2(u.p[q], wzK[4 * i + q], pz);
                        pr = fdot2(u.p[q], wrK[4 * i + q], pr);
                        ph = fdot2(u.p[q], whK[4 * i + q], ph);
                    }
                }
                xz = quad_sum(pz) + bzK;
                xr = quad_sum(pr) + brK;
                xh = quad_sum(ph) + bhK;
            }

            soft_barrier();   // lgkm-only: global loads/stores stay in flight
        }
    }

    // final publish
    __syncthreads();
    if (t == 0 && layer < 2)
        __hip_atomic_store(myflag, T, __ATOMIC_RELEASE, __HIP_MEMORY_SCOPE_AGENT);
}

// ---------------------------------------------------------------------------
// out_proj: out[r,:] = h_f16[r,:] @ wo + bo (fp32 out). Thread = row.
// ---------------------------------------------------------------------------
__global__ __launch_bounds__(256) void out_proj(
    const _Float16* __restrict__ Hf,  // [R,128] f16
    const float* __restrict__ wo,     // [128,5]
    const float* __restrict__ bo,     // [5]
    float*       __restrict__ out,    // [R,5]
    int R)
{
    const int r = blockIdx.x * 256 + threadIdx.x;
    if (r >= R) return;
    const f16x8* xp = (const f16x8*)(Hf + (size_t)r * HID);

    float a0 = bo[0], a1 = bo[1], a2 = bo[2], a3 = bo[3], a4 = bo[4];
#pragma unroll 4
    for (int c = 0; c < 16; ++c) {
        const f16x8 v = xp[c];
#pragma unroll
        for (int e = 0; e < 8; ++e) {
            const float xv = (float)v[e];
            const float* w = wo + (size_t)(8 * c + e) * OUTD;
            a0 = fmaf(xv, w[0], a0);
            a1 = fmaf(xv, w[1], a1);
            a2 = fmaf(xv, w[2], a2);
            a3 = fmaf(xv, w[3], a3);
            a4 = fmaf(xv, w[4], a4);
        }
    }
    float* op = out + (size_t)r * OUTD;
    op[0] = a0; op[1] = a1; op[2] = a2; op[3] = a3; op[4] = a4;
}

// ---------------------------------------------------------------------------
extern "C" void kernel_launch(void* const* d_in, const int* in_sizes, int n_in,
                              void* d_out, int out_size, void* d_ws, size_t ws_size,
                              hipStream_t stream) {
    const float* x   = (const float*)d_in[0];
    const float* k0  = (const float*)d_in[1];
    const float* rk0 = (const float*)d_in[2];
    const float* b0  = (const float*)d_in[3];
    const float* k1  = (const float*)d_in[4];
    const float* rk1 = (const float*)d_in[5];
    const float* b1  = (const float*)d_in[6];
    const float* k2  = (const float*)d_in[7];
    const float* rk2 = (const float*)d_in[8];
    const float* b2  = (const float*)d_in[9];
    const float* wo  = (const float*)d_in[10];
    const float* bo  = (const float*)d_in[11];
    float* out = (float*)d_out;

    const int BT = in_sizes[0] / HID;   // 64*2048 = 131072 rows
    const int B  = 64;
    const int T  = BT / B;              // 2048

    // ws layout: 3 h-planes f16 32MB each + flags
    const size_t plane = (size_t)BT * HID * sizeof(_Float16);
    _Float16* hpl0 = (_Float16*)d_ws;
    _Float16* hpl1 = (_Float16*)((char*)d_ws + plane);
    _Float16* hpl2 = (_Float16*)((char*)d_ws + 2 * plane);
    int*      flags = (int*)((char*)d_ws + 3 * plane);

    zero_flags<<<1, 256, 0, stream>>>(flags);
    gru_pipe  <<<192, 512, 0, stream>>>(x, k0, k1, k2, rk0, rk1, rk2,
                                        b0, b1, b2, hpl0, hpl1, hpl2, flags, T);
    out_proj  <<<(BT + 255) / 256, 256, 0, stream>>>(hpl2, wo, bo, out, BT);
}